// Round 1
// baseline (323.368 us; speedup 1.0000x reference)
//
#include <hip/hip_runtime.h>

// BasicCL4CTR: embedding gather + alignment/uniformity contrastive losses.
// B=4096 samples, F=39 fields, d=16. All field dims = 100000 -> offset[f] = f*100000.
// out = ( (B*sum(sq) - sum(s*s)) / (n_pairs*F)  +  mean_{b,f,g} frac/denom ) * BETA

#define BATCH   4096
#define NF      39
#define ED      16
#define SPB     8                   // samples per block
#define THREADS 256
#define NPAIRS  (NF * (NF + 1) / 2) // 780 pairs f<=g
#define ROWF    (NF * ED)           // 624 floats per sample
#define EPS     1e-4f
#define BETA    0.01

__global__ __launch_bounds__(THREADS) void cl4ctr_main(
    const int* __restrict__ x, const float* __restrict__ emb,
    float* __restrict__ s_glob,   // [624] batch-sum of embeddings
    float* __restrict__ scal)     // [0]=uniform_sum, [1]=sq_sum
{
    __shared__ __align__(16) float e[SPB][ROWF];   // 8 * 2496 B = ~20 KB
    __shared__ float norms[SPB][NF + 1];
    __shared__ int   sidx[SPB * NF];
    __shared__ float wred[2][4];

    const int tid = threadIdx.x;
    const int b0  = blockIdx.x * SPB;

    // ---- stage indices (contiguous, coalesced) ----
    for (int t = tid; t < SPB * NF; t += THREADS)
        sidx[t] = x[b0 * NF + t];
    __syncthreads();

    // ---- gather embeddings: 8*39 rows * 4 float4 = 1248 loads ----
    for (int p = tid; p < SPB * NF * 4; p += THREADS) {
        int si = p / (NF * 4);
        int r  = p - si * (NF * 4);
        int f  = r >> 2, q = r & 3;
        size_t row = (size_t)sidx[si * NF + f] + (size_t)f * 100000u;
        float4 v = *(const float4*)(emb + row * ED + q * 4);
        *(float4*)&e[si][f * ED + q * 4] = v;
    }
    __syncthreads();

    // ---- partial batch-sum s over this block's 8 samples -> global atomics ----
    for (int t = tid; t < ROWF; t += THREADS) {
        float a = 0.f;
#pragma unroll
        for (int si = 0; si < SPB; ++si) a += e[si][t];
        atomicAdd(&s_glob[t], a);
    }

    // ---- per-(sample,field) squared norms ----
    float sq_local = 0.f;
    for (int t = tid; t < SPB * NF; t += THREADS) {
        int si = t / NF, f = t - si * NF;
        const float4* r4 = (const float4*)&e[si][f * ED];
        float4 a = r4[0], b = r4[1], c = r4[2], d = r4[3];
        float sq = a.x*a.x + a.y*a.y + a.z*a.z + a.w*a.w
                 + b.x*b.x + b.y*b.y + b.z*b.z + b.w*b.w
                 + c.x*c.x + c.y*c.y + c.z*c.z + c.w*c.w
                 + d.x*d.x + d.y*d.y + d.z*d.z + d.w*d.w;
        norms[si][f] = sqrtf(sq);
        sq_local += sq;
    }
    __syncthreads();

    // ---- symmetric pair loop: 8 * 780 pairs, off-diag weighted 2x ----
    float uni = 0.f;
    for (int p = tid; p < SPB * NPAIRS; p += THREADS) {
        int si = p / NPAIRS;
        int k  = p - si * NPAIRS;
        // triangular decode: start(f) = f*(79-f)/2, exact at row starts
        int f = (int)((79.0f - sqrtf((float)(6241 - 8 * k))) * 0.5f);
        if (f > NF - 1) f = NF - 1;
        while (f * (79 - f) / 2 > k) --f;
        while ((f + 1) * (78 - f) / 2 <= k) ++f;
        int g = f + (k - f * (79 - f) / 2);

        const float4* rf = (const float4*)&e[si][f * ED];
        const float4* rg = (const float4*)&e[si][g * ED];
        float4 a0 = rf[0], a1 = rf[1], a2 = rf[2], a3 = rf[3];
        float4 b0 = rg[0], b1 = rg[1], b2 = rg[2], b3 = rg[3];
        float dot = a0.x*b0.x + a0.y*b0.y + a0.z*b0.z + a0.w*b0.w
                  + a1.x*b1.x + a1.y*b1.y + a1.z*b1.z + a1.w*b1.w
                  + a2.x*b2.x + a2.y*b2.y + a2.z*b2.z + a2.w*b2.w
                  + a3.x*b3.x + a3.y*b3.y + a3.z*b3.z + a3.w*b3.w;
        float w = (f == g) ? 1.f : 2.f;
        uni += w * dot / (norms[si][f] * norms[si][g] + EPS);
    }

    // ---- block reduce (64-wide wave shuffles, then cross-wave via LDS) ----
#pragma unroll
    for (int off = 32; off > 0; off >>= 1) {
        uni      += __shfl_down(uni, off, 64);
        sq_local += __shfl_down(sq_local, off, 64);
    }
    int lane = tid & 63, wv = tid >> 6;
    if (lane == 0) { wred[0][wv] = uni; wred[1][wv] = sq_local; }
    __syncthreads();
    if (tid == 0) {
        atomicAdd(&scal[0], wred[0][0] + wred[0][1] + wred[0][2] + wred[0][3]);
        atomicAdd(&scal[1], wred[1][0] + wred[1][1] + wred[1][2] + wred[1][3]);
    }
}

__global__ __launch_bounds__(256) void cl4ctr_final(
    const float* __restrict__ s_glob, const float* __restrict__ scal,
    float* __restrict__ out)
{
    __shared__ float wred[4];
    float ss = 0.f;
    for (int t = threadIdx.x; t < ROWF; t += 256) {
        float v = s_glob[t];
        ss += v * v;
    }
#pragma unroll
    for (int off = 32; off > 0; off >>= 1)
        ss += __shfl_down(ss, off, 64);
    int lane = threadIdx.x & 63, wv = threadIdx.x >> 6;
    if (lane == 0) wred[wv] = ss;
    __syncthreads();
    if (threadIdx.x == 0) {
        double sstot   = (double)wred[0] + wred[1] + wred[2] + wred[3];
        double uni_sum = (double)scal[0];
        double sq_sum  = (double)scal[1];
        double pair_sum = (double)BATCH * sq_sum - sstot;
        double n_pairs  = (double)BATCH * (BATCH - 1) / 2.0;
        double align_l  = pair_sum / (n_pairs * (double)NF);
        double uniform  = uni_sum / ((double)BATCH * NF * NF);
        out[0] = (float)((align_l + uniform) * BETA);
    }
}

extern "C" void kernel_launch(void* const* d_in, const int* in_sizes, int n_in,
                              void* d_out, int out_size, void* d_ws, size_t ws_size,
                              hipStream_t stream) {
    const int*   x   = (const int*)d_in[0];
    const float* emb = (const float*)d_in[1];
    float* out = (float*)d_out;
    float* ws  = (float*)d_ws;   // [0..623]=s, [624]=uniform_sum, [625]=sq_sum

    hipMemsetAsync(d_ws, 0, 2560, stream);
    cl4ctr_main<<<BATCH / SPB, THREADS, 0, stream>>>(x, emb, ws, ws + ROWF);
    cl4ctr_final<<<1, 256, 0, stream>>>(ws, ws + ROWF, out);
}

// Round 2
// 306.362 us; speedup vs baseline: 1.0555x; 1.0555x over previous
//
#include <hip/hip_runtime.h>

// BasicCL4CTR: embedding gather + alignment/uniformity contrastive losses.
// B=4096, F=39 fields, d=16. All field dims = 100000 -> offset[f] = f*100000.
// out = ( (B*sum(sq) - sum(s*s)) / (n_pairs*F) + mean_{b,f,g} frac/denom ) * BETA
//
// R2 changes vs R1:
//  - LDS field stride padded 16 -> 20 floats: breaks the {bank0,bank16}-only
//    pathology (16-way conflicts ~5.7x) on every pair-loop ds_read_b128.
//  - Pair loop restructured: triangular decode once per pair (~3/thread),
//    inner loop over the 8 samples (was: decode per sample*pair, 8x waste).

#define BATCH   4096
#define NF      39
#define ED      16
#define FS      20                  // padded field stride (floats); (f*20)%32 cycles 8 banks
#define SS      (FS * NF)           // sample stride = 780 floats (3120 B, 16B-aligned)
#define SPB     8                   // samples per block
#define THREADS 256
#define NPAIRS  (NF * (NF + 1) / 2) // 780 pairs f<=g
#define ROWF    (NF * ED)           // 624 dense floats per sample (s vector)
#define EPS     1e-4f
#define BETA    0.01

__global__ __launch_bounds__(THREADS) void cl4ctr_main(
    const int* __restrict__ x, const float* __restrict__ emb,
    float* __restrict__ s_glob,   // [624] batch-sum of embeddings
    float* __restrict__ scal)     // [0]=uniform_sum, [1]=sq_sum
{
    __shared__ __align__(16) float e[SPB * SS];    // 8*780*4 B = 24.4 KB, padded
    __shared__ float norms[SPB][NF + 1];
    __shared__ int   sidx[SPB * NF];
    __shared__ float wred[2][4];

    const int tid = threadIdx.x;
    const int b0  = blockIdx.x * SPB;

    // ---- stage indices (contiguous, coalesced) ----
    for (int t = tid; t < SPB * NF; t += THREADS)
        sidx[t] = x[b0 * NF + t];
    __syncthreads();

    // ---- gather embeddings: 8*39 rows * 4 float4; 4 consecutive lanes share a 64B row ----
    for (int p = tid; p < SPB * NF * 4; p += THREADS) {
        int si = p / (NF * 4);
        int r  = p - si * (NF * 4);
        int f  = r >> 2, q = r & 3;
        size_t row = (size_t)sidx[si * NF + f] + (size_t)f * 100000u;
        float4 v = *(const float4*)(emb + row * ED + q * 4);
        *(float4*)&e[si * SS + f * FS + q * 4] = v;
    }
    __syncthreads();

    // ---- partial batch-sum s over this block's 8 samples -> global atomics ----
    // (issued early; fire-and-forget atomics drain while the pair loop computes)
    for (int t = tid; t < ROWF; t += THREADS) {
        int f = t >> 4, d = t & 15;
        float a = 0.f;
#pragma unroll
        for (int si = 0; si < SPB; ++si) a += e[si * SS + f * FS + d];
        atomicAdd(&s_glob[t], a);
    }

    // ---- per-(sample,field) squared norms ----
    float sq_local = 0.f;
    for (int t = tid; t < SPB * NF; t += THREADS) {
        int si = t / NF, f = t - si * NF;
        const float4* r4 = (const float4*)&e[si * SS + f * FS];
        float4 a = r4[0], b = r4[1], c = r4[2], d = r4[3];
        float sq = a.x*a.x + a.y*a.y + a.z*a.z + a.w*a.w
                 + b.x*b.x + b.y*b.y + b.z*b.z + b.w*b.w
                 + c.x*c.x + c.y*c.y + c.z*c.z + c.w*c.w
                 + d.x*d.x + d.y*d.y + d.z*d.z + d.w*d.w;
        norms[si][f] = sqrtf(sq);
        sq_local += sq;
    }
    __syncthreads();

    // ---- symmetric pair loop: decode once per pair, inner loop over samples ----
    float uni = 0.f;
    for (int p = tid; p < NPAIRS; p += THREADS) {
        // triangular decode: start(f) = f*(79-f)/2
        int f = (int)((79.0f - sqrtf((float)(6241 - 8 * p))) * 0.5f);
        if (f > NF - 1) f = NF - 1;
        while (f * (79 - f) / 2 > p) --f;
        while ((f + 1) * (78 - f) / 2 <= p) ++f;
        int g = f + (p - f * (79 - f) / 2);
        float w = (f == g) ? 1.f : 2.f;
        int offf = f * FS, offg = g * FS;

#pragma unroll
        for (int si = 0; si < SPB; ++si) {
            const float4* rf = (const float4*)&e[si * SS + offf];
            const float4* rg = (const float4*)&e[si * SS + offg];
            float4 a0 = rf[0], a1 = rf[1], a2 = rf[2], a3 = rf[3];
            float4 b0 = rg[0], b1 = rg[1], b2 = rg[2], b3 = rg[3];
            float dot = a0.x*b0.x + a0.y*b0.y + a0.z*b0.z + a0.w*b0.w
                      + a1.x*b1.x + a1.y*b1.y + a1.z*b1.z + a1.w*b1.w
                      + a2.x*b2.x + a2.y*b2.y + a2.z*b2.z + a2.w*b2.w
                      + a3.x*b3.x + a3.y*b3.y + a3.z*b3.z + a3.w*b3.w;
            uni += w * dot / (norms[si][f] * norms[si][g] + EPS);
        }
    }

    // ---- block reduce (64-wide wave shuffles, then cross-wave via LDS) ----
#pragma unroll
    for (int off = 32; off > 0; off >>= 1) {
        uni      += __shfl_down(uni, off, 64);
        sq_local += __shfl_down(sq_local, off, 64);
    }
    int lane = tid & 63, wv = tid >> 6;
    if (lane == 0) { wred[0][wv] = uni; wred[1][wv] = sq_local; }
    __syncthreads();
    if (tid == 0) {
        atomicAdd(&scal[0], wred[0][0] + wred[0][1] + wred[0][2] + wred[0][3]);
        atomicAdd(&scal[1], wred[1][0] + wred[1][1] + wred[1][2] + wred[1][3]);
    }
}

__global__ __launch_bounds__(256) void cl4ctr_final(
    const float* __restrict__ s_glob, const float* __restrict__ scal,
    float* __restrict__ out)
{
    __shared__ float wred[4];
    float ss = 0.f;
    for (int t = threadIdx.x; t < ROWF; t += 256) {
        float v = s_glob[t];
        ss += v * v;
    }
#pragma unroll
    for (int off = 32; off > 0; off >>= 1)
        ss += __shfl_down(ss, off, 64);
    int lane = threadIdx.x & 63, wv = threadIdx.x >> 6;
    if (lane == 0) wred[wv] = ss;
    __syncthreads();
    if (threadIdx.x == 0) {
        double sstot   = (double)wred[0] + wred[1] + wred[2] + wred[3];
        double uni_sum = (double)scal[0];
        double sq_sum  = (double)scal[1];
        double pair_sum = (double)BATCH * sq_sum - sstot;
        double n_pairs  = (double)BATCH * (BATCH - 1) / 2.0;
        double align_l  = pair_sum / (n_pairs * (double)NF);
        double uniform  = uni_sum / ((double)BATCH * NF * NF);
        out[0] = (float)((align_l + uniform) * BETA);
    }
}

extern "C" void kernel_launch(void* const* d_in, const int* in_sizes, int n_in,
                              void* d_out, int out_size, void* d_ws, size_t ws_size,
                              hipStream_t stream) {
    const int*   x   = (const int*)d_in[0];
    const float* emb = (const float*)d_in[1];
    float* out = (float*)d_out;
    float* ws  = (float*)d_ws;   // [0..623]=s, [624]=uniform_sum, [625]=sq_sum

    hipMemsetAsync(d_ws, 0, 2560, stream);
    cl4ctr_main<<<BATCH / SPB, THREADS, 0, stream>>>(x, emb, ws, ws + ROWF);
    cl4ctr_final<<<1, 256, 0, stream>>>(ws, ws + ROWF, out);
}